// Round 13
// baseline (322.205 us; speedup 1.0000x reference)
//
#include <hip/hip_runtime.h>
#include <hip/hip_fp16.h>
#include <math.h>

#define F_IN 256
#define HC 64
#define NHEAD 8
#define NEG 0.2f
#define BSH 7
#define BSZ 128            // dsts per bucket (partition layout)
#define CAP 5376           // slack slots per bucket (mean ~4096, +20 sigma)
#define HCAP 2944          // per-half-bucket sort capacity (mean 2048, +19.8 sigma)

typedef __attribute__((ext_vector_type(8))) short bf16x8;
typedef __attribute__((ext_vector_type(4))) float f32x4;

union BV { uint4 q; bf16x8 v; };

// pack two floats' bf16-truncated high halves into one dword via v_perm_b32.
__device__ __forceinline__ unsigned int hi_pair(float a, float b) {
  return __builtin_amdgcn_perm(__float_as_uint(a), __float_as_uint(b), 0x03020706u);
}
// residuals after truncation (lo captures what hi dropped; hi*hi+hi*lo+lo*hi
// reconstructs fp32-accurate product, err ~2^-14 rel).
__device__ __forceinline__ unsigned int lo_pair(float a, float b) {
  float ra = a - __uint_as_float(__float_as_uint(a) & 0xffff0000u);
  float rb = b - __uint_as_float(__float_as_uint(b) & 0xffff0000u);
  return __builtin_amdgcn_perm(__float_as_uint(ra), __float_as_uint(rb), 0x03020706u);
}

// W fp32 [256][64] -> bf16 hi/lo in MFMA B-fragment order; also zero bcursor.
__global__ __launch_bounds__(256) void k_prep(const float* __restrict__ W,
                                              unsigned short* __restrict__ Wp,
                                              int* __restrict__ bcursor, int NB) {
  int b = blockIdx.x, t = threadIdx.x;
  if (b >= 64) {
    int i = (b - 64) * 256 + t;
    if (i < NB) bcursor[i] = 0;
    return;
  }
  int idx = b * 256 + t;  // 16384 = 256*64 elements, one per thread
  int k = idx >> 6, c = idx & 63;
  float w = W[idx];
  unsigned int u = __float_as_uint(w);
  unsigned short hi = (unsigned short)((u + 0x7fffu + ((u >> 16) & 1u)) >> 16);  // RNE
  float r = w - __uint_as_float((unsigned int)hi << 16);
  unsigned int ur = __float_as_uint(r);
  unsigned short lo = (unsigned short)((ur + 0x7fffu + ((ur >> 16) & 1u)) >> 16);
  int ks = k >> 5, j = k & 7, lg = (k >> 3) & 3;
  int lane = lg * 16 + (c & 15), cg = c >> 4;
  int off = ((ks * 4 + cg) * 64 + lane) * 8 + j;
  Wp[off] = hi;
  Wp[16384 + off] = lo;
}

// STANDALONE staged MFMA GEMM (unfused from partition). Rationale: R8 showed
// fusion gave ZERO overlap (fused ~= serial sum) -- co-residency just
// time-sliced the CU -- while the partition half's 78KB static LDS capped the
// gemm half and its LDS-atomic storm contended with gemm's staging traffic.
// Solo: 64KB LDS -> 2 blocks/CU, all 391 blocks co-resident (<512 slots) ->
// one batch, x-stream BW-bound (102.4MB / 6.3TB/s ~= 16us floor).
// Structure = R12 gemm half verbatim: 8 waves x 32 rows = 256 rows/block,
// 2x32KB double buffer, 2-phase pipeline {STAGE(next); compute(cur); barrier},
// pre-swizzled global source + XOR-swizzled ds_read (granule ^= row&7).
__global__ __launch_bounds__(512, 4) void k_gemm(
    const float* __restrict__ x, const uint4* __restrict__ Wp4,
    const float* __restrict__ att_src, const float* __restrict__ att_dst,
    __half2* __restrict__ h2, float* __restrict__ asrc, float* __restrict__ adst,
    int N) {
  __shared__ __align__(16) char xb[65536];  // 2 x 32KB staging buffers
  int t = threadIdx.x;
  int wv = t >> 6, l = t & 63;
  int lr = l & 15, lg = l >> 4;
  int r0blk = blockIdx.x * 256;

  float as4[4], ad4[4];
#pragma unroll
  for (int cg = 0; cg < 4; cg++) {
    as4[cg] = att_src[cg * 16 + lr];
    ad4[cg] = att_dst[cg * 16 + lr];
  }
  const uint4* wp = Wp4 + l;

  f32x4 acc[2][4];
#pragma unroll
  for (int i = 0; i < 2; i++)
#pragma unroll
    for (int j = 0; j < 4; j++) acc[i][j] = (f32x4){0.f, 0.f, 0.f, 0.f};

  // stage tile ks into buffer buf: 4 rounds x 512 thr x 16B = 32KB.
  // LDS dest linear (wave-uniform base, lane x16 implicit); global source
  // pre-swizzled so slot (r, G) holds source granule g = G ^ (r&7).
#define STAGE(ks_, buf_)                                                        \
  {                                                                             \
    _Pragma("unroll")                                                           \
    for (int rd = 0; rd < 4; rd++) {                                            \
      int Lbase = rd * 512 + wv * 64;                                           \
      int L = Lbase + l;                                                        \
      int r_ = L >> 3;                                                          \
      int g_ = (L & 7) ^ (r_ & 7);                                              \
      int grow = r0blk + r_; if (grow > N - 1) grow = N - 1;                    \
      __builtin_amdgcn_global_load_lds(                                         \
          (const void*)(x + (size_t)grow * F_IN + (ks_) * 32 + g_ * 4),         \
          (void*)(xb + (buf_) * 32768 + (size_t)Lbase * 16), 16, 0, 0);         \
    }                                                                           \
  }

  STAGE(0, 0);
  __syncthreads();   // tile 0 landed (vmcnt drained at this barrier)
  int ra_t = wv * 32 + lr, rb_t = ra_t + 16;   // rb_t&7 == ra_t&7 (same swizzle)
  int s0 = ra_t * 8 + ((lg * 2 + 0) ^ (ra_t & 7));
  int s1 = ra_t * 8 + ((lg * 2 + 1) ^ (ra_t & 7));
  int s2 = rb_t * 8 + ((lg * 2 + 0) ^ (rb_t & 7));
  int s3 = rb_t * 8 + ((lg * 2 + 1) ^ (rb_t & 7));

#pragma unroll
  for (int ks = 0; ks < 8; ks++) {
    if (ks < 7) STAGE(ks + 1, (ks + 1) & 1);   // prefetch flies during compute
    const char* cb = xb + (ks & 1) * 32768;
    float4 p0 = *(const float4*)(cb + (size_t)s0 * 16);
    float4 q0 = *(const float4*)(cb + (size_t)s1 * 16);
    float4 p1 = *(const float4*)(cb + (size_t)s2 * 16);
    float4 q1 = *(const float4*)(cb + (size_t)s3 * 16);
    BV bh[4], bl[4];
#pragma unroll
    for (int cg = 0; cg < 4; cg++) {
      bh[cg].q = wp[(ks * 4 + cg) * 64];
      bl[cg].q = wp[2048 + (ks * 4 + cg) * 64];
    }
    BV ah0, al0, ah1, al1;
    ah0.q.x = hi_pair(p0.x, p0.y); ah0.q.y = hi_pair(p0.z, p0.w);
    ah0.q.z = hi_pair(q0.x, q0.y); ah0.q.w = hi_pair(q0.z, q0.w);
    al0.q.x = lo_pair(p0.x, p0.y); al0.q.y = lo_pair(p0.z, p0.w);
    al0.q.z = lo_pair(q0.x, q0.y); al0.q.w = lo_pair(q0.z, q0.w);
    ah1.q.x = hi_pair(p1.x, p1.y); ah1.q.y = hi_pair(p1.z, p1.w);
    ah1.q.z = hi_pair(q1.x, q1.y); ah1.q.w = hi_pair(q1.z, q1.w);
    al1.q.x = lo_pair(p1.x, p1.y); al1.q.y = lo_pair(p1.z, p1.w);
    al1.q.z = lo_pair(q1.x, q1.y); al1.q.w = lo_pair(q1.z, q1.w);
#pragma unroll
    for (int cg = 0; cg < 4; cg++) {
      acc[0][cg] = __builtin_amdgcn_mfma_f32_16x16x32_bf16(ah0.v, bh[cg].v, acc[0][cg], 0, 0, 0);
      acc[0][cg] = __builtin_amdgcn_mfma_f32_16x16x32_bf16(al0.v, bh[cg].v, acc[0][cg], 0, 0, 0);
      acc[0][cg] = __builtin_amdgcn_mfma_f32_16x16x32_bf16(ah0.v, bl[cg].v, acc[0][cg], 0, 0, 0);
      acc[1][cg] = __builtin_amdgcn_mfma_f32_16x16x32_bf16(ah1.v, bh[cg].v, acc[1][cg], 0, 0, 0);
      acc[1][cg] = __builtin_amdgcn_mfma_f32_16x16x32_bf16(al1.v, bh[cg].v, acc[1][cg], 0, 0, 0);
      acc[1][cg] = __builtin_amdgcn_mfma_f32_16x16x32_bf16(ah1.v, bl[cg].v, acc[1][cg], 0, 0, 0);
    }
    __syncthreads();   // prefetch landed for all waves + WAR protection
  }
#undef STAGE

  // epilogue. C/D layout: col = cg*16 + lr, row(node) = rg*16 + 4*lg + tt.
  int r0 = r0blk + wv * 32;
#pragma unroll
  for (int rg = 0; rg < 2; rg++) {
#pragma unroll
    for (int tt = 0; tt < 4; tt++) {
      int node = r0 + rg * 16 + 4 * lg + tt;
      bool ok = node < N;
      float v0 = acc[rg][0][tt], v1 = acc[rg][1][tt], v2 = acc[rg][2][tt], v3 = acc[rg][3][tt];
      float o0 = __shfl_xor(v0, 1), o1 = __shfl_xor(v1, 1);
      float o2 = __shfl_xor(v2, 1), o3 = __shfl_xor(v3, 1);
      if (ok && !(l & 1)) {
        size_t hb = (size_t)node * 32 + (lr >> 1);
        h2[hb]      = __halves2half2(__float2half_rn(v0), __float2half_rn(o0));
        h2[hb + 8]  = __halves2half2(__float2half_rn(v1), __float2half_rn(o1));
        h2[hb + 16] = __halves2half2(__float2half_rn(v2), __float2half_rn(o2));
        h2[hb + 24] = __halves2half2(__float2half_rn(v3), __float2half_rn(o3));
      }
#pragma unroll
      for (int cg = 0; cg < 4; cg++) {
        float v = (cg == 0) ? v0 : (cg == 1) ? v1 : (cg == 2) ? v2 : v3;
        float s = v * as4[cg];
        float d = v * ad4[cg];
        s += __shfl_xor(s, 1); d += __shfl_xor(d, 1);
        s += __shfl_xor(s, 2); d += __shfl_xor(d, 2);
        s += __shfl_xor(s, 4); d += __shfl_xor(d, 4);
        if (ok && !(l & 7)) {
          int hd = 2 * cg + (lr >> 3);
          asrc[node * NHEAD + hd] = s;
          adst[node * NHEAD + hd] = d;
        }
      }
    }
  }
}

// partition edges into slack bucket layout; LDS reorder -> coalesced-run writes.
// (R2 version verbatim, standalone again. R4's direct-scatter regressed via
// write amplification; R8-R12 fusion with gemm gave zero overlap.)
// entry = ((dst & 127) << 17) | src  (src < 2^17). One global atomic per (chunk, nonzero bucket).
__global__ __launch_bounds__(512) void k_partition(
    const int* __restrict__ edge, int* __restrict__ bcursor,
    unsigned int* __restrict__ entries, int E, int NB) {
  __shared__ unsigned long long srt8[8192];  // 64 KB
  __shared__ int hist[1024];
  __shared__ int loff[1024];
  __shared__ int basearr[1024];
  __shared__ int pr[512];
  int t = threadIdx.x;
  int base = blockIdx.x * 8192;
  int cblk = min(8192, E - base);
  for (int i = t; i < 1024; i += 512) hist[i] = 0;
  __syncthreads();
#pragma unroll
  for (int j = 0; j < 16; j++) {
    int e = base + j * 512 + t;
    if (e < E) atomicAdd(&hist[edge[E + e] >> BSH], 1);
  }
  __syncthreads();
  int a = hist[2 * t], b = hist[2 * t + 1];
  pr[t] = a + b;
  __syncthreads();
  for (int off = 1; off < 512; off <<= 1) {
    int add = (t >= off) ? pr[t - off] : 0;
    __syncthreads();
    pr[t] += add;
    __syncthreads();
  }
  int excl = pr[t] - (a + b);
  loff[2 * t] = excl;
  loff[2 * t + 1] = excl + a;
  if (a > 0 && 2 * t < NB) basearr[2 * t] = atomicAdd(&bcursor[2 * t], a);
  if (b > 0 && 2 * t + 1 < NB) basearr[2 * t + 1] = atomicAdd(&bcursor[2 * t + 1], b);
  hist[2 * t] = excl;           // reuse hist as LDS scatter cursor
  hist[2 * t + 1] = excl + a;
  __syncthreads();
#pragma unroll
  for (int j = 0; j < 16; j++) {
    int e = base + j * 512 + t;
    if (e < E) {
      int s = edge[e], d = edge[E + e];
      int p = atomicAdd(&hist[d >> BSH], 1);
      srt8[p] = ((unsigned long long)(unsigned int)d << 32) | (unsigned int)s;
    }
  }
  __syncthreads();
  for (int i = t; i < cblk; i += 512) {
    unsigned long long v = srt8[i];
    int d = (int)(v >> 32), s = (int)(v & 0xFFFFFFFFu);
    int bk = d >> BSH;
    int local = basearr[bk] + (i - loff[bk]);
    if (local < CAP)
      entries[(size_t)bk * CAP + local] = ((unsigned int)(d & (BSZ - 1)) << 17) | (unsigned int)s;
  }
}

// TWO blocks per bucket, split by DST-HALF (R12 best: 4-way split regressed
// 93->108 -- full-bucket scans doubled sort overhead). Block 2*bkt+hf owns
// local dsts [64*hf, 64*hf+64); each edge gathered ONCE. Grid 1564, LDS 13 KB.
// Per-wave agg: lane l = (edge-slot l>>3, head l&7), ONE uint4 h2 load +
// ONE asrc load + ONE exp per edge-lane. Plateaued at the gather-latency
// structural limit (warm-replay == cold).
__global__ __launch_bounds__(512, 6) void k_bagg(
    const unsigned int* __restrict__ entries, const int* __restrict__ bcursor,
    const __half2* __restrict__ h2, const float* __restrict__ asrc,
    const float* __restrict__ adst, const float* __restrict__ bias,
    float* __restrict__ out, int N) {
  __shared__ int srt[HCAP];
  __shared__ int hist[64];
  __shared__ int cur[64];
  __shared__ int off[65];
  __shared__ int tmp[64];
  int t = threadIdx.x;
  int bkt = blockIdx.x >> 1;
  int hf = blockIdx.x & 1;
  int n0 = (bkt << BSH) + (hf << 6);
  int ncnt = min(64, N - n0);
  if (ncnt <= 0) return;  // uniform across block: safe before barriers
  int cnt = bcursor[bkt];
  if (cnt > CAP) cnt = CAP;
  const unsigned int* ebase = entries + (size_t)bkt * CAP;
  if (t < 64) hist[t] = 0;
  __syncthreads();
  // histogram of this half's local dsts (full-bucket scan, predicated)
  for (int i = t; i < cnt; i += 512) {
    int d = (int)(ebase[i] >> 17);
    if ((d >> 6) == hf) atomicAdd(&hist[d & 63], 1);
  }
  __syncthreads();
  if (t < 64) tmp[t] = hist[t];
  __syncthreads();
  for (int o = 1; o < 64; o <<= 1) {
    int add = (t < 64 && t >= o) ? tmp[t - o] : 0;
    __syncthreads();
    if (t < 64) tmp[t] += add;
    __syncthreads();
  }
  if (t < 64) { off[t] = tmp[t] - hist[t]; cur[t] = tmp[t] - hist[t]; }
  if (t == 63) off[64] = tmp[63];
  __syncthreads();
  for (int i = t; i < cnt; i += 512) {
    unsigned int v = ebase[i];
    int d = (int)(v >> 17);
    if ((d >> 6) == hf) {
      int p = atomicAdd(&cur[d & 63], 1);
      if (p < HCAP) srt[p] = (int)(v & 0x1FFFF);
    }
  }
  __syncthreads();
  int wv = t >> 6, l = t & 63;
  int eslot = l >> 3, cg = l & 7;
  for (int nd = wv; nd < ncnt; nd += 8) {
    int node = n0 + nd;
    int sbeg = min(off[nd], HCAP), send = min(off[nd + 1], HCAP);
    float ad = adst[node * NHEAD + cg];
    float a0 = 0.f, a1 = 0.f, a2 = 0.f, a3 = 0.f;
    float a4 = 0.f, a5 = 0.f, a6 = 0.f, a7 = 0.f;
    float wsum = 0.f;
    for (int k = sbeg; k < send; k += 8) {
      int idx = k + eslot;
      bool val = idx < send;
      int s = srt[val ? idx : send - 1];
      float lg = asrc[s * NHEAD + cg] + ad;
      float w = __expf(fmaxf(lg, NEG * lg));
      w = val ? w : 0.f;
      union { uint4 q; __half2 h[4]; } u;
      u.q = *((const uint4*)(h2 + (size_t)s * 32) + cg);
      float2 f0 = __half22float2(u.h[0]);
      float2 f1 = __half22float2(u.h[1]);
      float2 f2 = __half22float2(u.h[2]);
      float2 f3 = __half22float2(u.h[3]);
      a0 = fmaf(w, f0.x, a0); a1 = fmaf(w, f0.y, a1);
      a2 = fmaf(w, f1.x, a2); a3 = fmaf(w, f1.y, a3);
      a4 = fmaf(w, f2.x, a4); a5 = fmaf(w, f2.y, a5);
      a6 = fmaf(w, f3.x, a6); a7 = fmaf(w, f3.y, a7);
      wsum += w;
    }
#pragma unroll
    for (int m = 8; m < 64; m <<= 1) {
      a0 += __shfl_xor(a0, m); a1 += __shfl_xor(a1, m);
      a2 += __shfl_xor(a2, m); a3 += __shfl_xor(a3, m);
      a4 += __shfl_xor(a4, m); a5 += __shfl_xor(a5, m);
      a6 += __shfl_xor(a6, m); a7 += __shfl_xor(a7, m);
      wsum += __shfl_xor(wsum, m);
    }
    if (l < 8) {
      float inv = wsum > 0.f ? 1.0f / wsum : 0.f;
      float4 b0 = *(const float4*)&bias[cg * 8];
      float4 b1 = *(const float4*)&bias[cg * 8 + 4];
      float4 r0, r1;
      r0.x = fmaf(a0, inv, b0.x); r0.y = fmaf(a1, inv, b0.y);
      r0.z = fmaf(a2, inv, b0.z); r0.w = fmaf(a3, inv, b0.w);
      r1.x = fmaf(a4, inv, b1.x); r1.y = fmaf(a5, inv, b1.y);
      r1.z = fmaf(a6, inv, b1.z); r1.w = fmaf(a7, inv, b1.w);
      *(float4*)&out[(size_t)node * HC + cg * 8] = r0;
      *(float4*)&out[(size_t)node * HC + cg * 8 + 4] = r1;
    }
  }
}

extern "C" void kernel_launch(void* const* d_in, const int* in_sizes, int n_in,
                              void* d_out, int out_size, void* d_ws, size_t ws_size,
                              hipStream_t stream) {
  const float* x = (const float*)d_in[0];
  const int* edge = (const int*)d_in[1];
  const float* W = (const float*)d_in[2];
  const float* att_src = (const float*)d_in[3];
  const float* att_dst = (const float*)d_in[4];
  const float* bias = (const float*)d_in[5];
  int N = in_sizes[0] / F_IN;
  int E = in_sizes[1] / 2;
  float* out = (float*)d_out;
  int NB = (N + BSZ - 1) >> BSH;

  // workspace layout (Wp first: keeps 16B alignment for uint4 fragment loads)
  unsigned short* Wp = (unsigned short*)d_ws;             // 32768 bf16 = 64 KB
  __half2* h2 = (__half2*)((char*)d_ws + 65536);          // N*32 half2 (= N*64 fp16)
  float* asrc = (float*)(h2 + (size_t)N * 32);            // N*8
  float* adst = asrc + (size_t)N * NHEAD;                 // N*8
  int* bcursor = (int*)(adst + (size_t)N * NHEAD);        // NB (padded to 16B)
  unsigned int* entries = (unsigned int*)(bcursor + ((NB + 3) & ~3));  // NB*CAP

  int NG = (N + 255) / 256;       // gemm blocks (256 rows each)
  int NP = (E + 8191) / 8192;     // partition chunks
  int nzb = (NB + 255) / 256;

  k_prep<<<64 + nzb, 256, 0, stream>>>(W, Wp, bcursor, NB);
  k_gemm<<<NG, 512, 0, stream>>>(x, (const uint4*)Wp, att_src, att_dst, h2, asrc, adst, N);
  k_partition<<<NP, 512, 0, stream>>>(edge, bcursor, entries, E, NB);
  k_bagg<<<2 * NB, 512, 0, stream>>>(entries, bcursor, h2, asrc, adst, bias, out, N);
}

// Round 14
// 298.863 us; speedup vs baseline: 1.0781x; 1.0781x over previous
//
#include <hip/hip_runtime.h>
#include <hip/hip_fp16.h>
#include <math.h>

#define F_IN 256
#define HC 64
#define NHEAD 8
#define NEG 0.2f
#define BSH 7
#define BSZ 128            // dsts per bucket (partition layout)
#define CAP 5376           // slack slots per bucket (mean ~4096, +20 sigma)
#define HCAP 2944          // per-half-bucket sort capacity (mean 2048, +19.8 sigma)

typedef __attribute__((ext_vector_type(8))) short bf16x8;
typedef __attribute__((ext_vector_type(4))) float f32x4;

union BV { uint4 q; bf16x8 v; };

// pack two floats' bf16-truncated high halves into one dword via v_perm_b32.
__device__ __forceinline__ unsigned int hi_pair(float a, float b) {
  return __builtin_amdgcn_perm(__float_as_uint(a), __float_as_uint(b), 0x03020706u);
}
// residuals after truncation (lo captures what hi dropped; hi*hi+hi*lo+lo*hi
// reconstructs fp32-accurate product, err ~2^-14 rel).
__device__ __forceinline__ unsigned int lo_pair(float a, float b) {
  float ra = a - __uint_as_float(__float_as_uint(a) & 0xffff0000u);
  float rb = b - __uint_as_float(__float_as_uint(b) & 0xffff0000u);
  return __builtin_amdgcn_perm(__float_as_uint(ra), __float_as_uint(rb), 0x03020706u);
}

// W fp32 [256][64] -> bf16 hi/lo in MFMA B-fragment order; also zero bcursor.
__global__ __launch_bounds__(256) void k_prep(const float* __restrict__ W,
                                              unsigned short* __restrict__ Wp,
                                              int* __restrict__ bcursor, int NB) {
  int b = blockIdx.x, t = threadIdx.x;
  if (b >= 64) {
    int i = (b - 64) * 256 + t;
    if (i < NB) bcursor[i] = 0;
    return;
  }
  int idx = b * 256 + t;  // 16384 = 256*64 elements, one per thread
  int k = idx >> 6, c = idx & 63;
  float w = W[idx];
  unsigned int u = __float_as_uint(w);
  unsigned short hi = (unsigned short)((u + 0x7fffu + ((u >> 16) & 1u)) >> 16);  // RNE
  float r = w - __uint_as_float((unsigned int)hi << 16);
  unsigned int ur = __float_as_uint(r);
  unsigned short lo = (unsigned short)((ur + 0x7fffu + ((ur >> 16) & 1u)) >> 16);
  int ks = k >> 5, j = k & 7, lg = (k >> 3) & 3;
  int lane = lg * 16 + (c & 15), cg = c >> 4;
  int off = ((ks * 4 + cg) * 64 + lane) * 8 + j;
  Wp[off] = hi;
  Wp[16384 + off] = lo;
}

// FUSED gemm+partition (R12-exact revert: unfusing regressed +15.5us -- solo,
// each kernel's 391 blocks land ~1.5/CU, machine half-empty; fused 782 blocks
// fill both LDS slots). 2-phase pipeline {STAGE(next); compute(cur); barrier}.
__global__ __launch_bounds__(512, 4) void k_fused(
    const float* __restrict__ x, const uint4* __restrict__ Wp4,
    const float* __restrict__ att_src, const float* __restrict__ att_dst,
    __half2* __restrict__ h2, float* __restrict__ asrc, float* __restrict__ adst,
    const int* __restrict__ edge, int* __restrict__ bcursor,
    unsigned int* __restrict__ entries, int N, int E, int NB, int NG, int NP) {
  __shared__ __align__(16) unsigned long long srt8[8192];  // 64 KB (partition sort / gemm x dbuf)
  __shared__ int hist[1024];
  __shared__ int loff[1024];
  __shared__ int basearr[1024];
  __shared__ int pr[512];
  int b = blockIdx.x;
  int mn = min(NG, NP), m2 = 2 * mn;
  int type, idx;
  if (b < m2) { type = b & 1; idx = b >> 1; }
  else { type = (NG > NP) ? 0 : 1; idx = mn + (b - m2); }
  int t = threadIdx.x;

  if (type == 0) {
    // ================= gemm half (LDS-staged, 2-phase pipelined) =================
    int wv = t >> 6, l = t & 63;
    int lr = l & 15, lg = l >> 4;
    int r0blk = idx * 256;
    char* xb = (char*)srt8;  // 2 x 32KB staging buffers

    float as4[4], ad4[4];
#pragma unroll
    for (int cg = 0; cg < 4; cg++) {
      as4[cg] = att_src[cg * 16 + lr];
      ad4[cg] = att_dst[cg * 16 + lr];
    }
    const uint4* wp = Wp4 + l;

    f32x4 acc[2][4];
#pragma unroll
    for (int i = 0; i < 2; i++)
#pragma unroll
      for (int j = 0; j < 4; j++) acc[i][j] = (f32x4){0.f, 0.f, 0.f, 0.f};

    // stage tile ks into buffer buf: 4 rounds x 512 thr x 16B = 32KB.
    // LDS dest linear (wave-uniform base, lane x16 implicit); global source
    // pre-swizzled so slot (r, G) holds source granule g = G ^ (r&7).
#define STAGE(ks_, buf_)                                                        \
    {                                                                           \
      _Pragma("unroll")                                                         \
      for (int rd = 0; rd < 4; rd++) {                                          \
        int Lbase = rd * 512 + wv * 64;                                         \
        int L = Lbase + l;                                                      \
        int r_ = L >> 3;                                                        \
        int g_ = (L & 7) ^ (r_ & 7);                                            \
        int grow = r0blk + r_; if (grow > N - 1) grow = N - 1;                  \
        __builtin_amdgcn_global_load_lds(                                       \
            (const void*)(x + (size_t)grow * F_IN + (ks_) * 32 + g_ * 4),       \
            (void*)(xb + (buf_) * 32768 + (size_t)Lbase * 16), 16, 0, 0);       \
      }                                                                         \
    }

    STAGE(0, 0);
    __syncthreads();   // tile 0 landed (vmcnt drained at this barrier)
    int ra_t = wv * 32 + lr, rb_t = ra_t + 16;   // rb_t&7 == ra_t&7 (same swizzle)
    int s0 = ra_t * 8 + ((lg * 2 + 0) ^ (ra_t & 7));
    int s1 = ra_t * 8 + ((lg * 2 + 1) ^ (ra_t & 7));
    int s2 = rb_t * 8 + ((lg * 2 + 0) ^ (rb_t & 7));
    int s3 = rb_t * 8 + ((lg * 2 + 1) ^ (rb_t & 7));

#pragma unroll
    for (int ks = 0; ks < 8; ks++) {
      if (ks < 7) STAGE(ks + 1, (ks + 1) & 1);   // prefetch flies during compute
      const char* cb = xb + (ks & 1) * 32768;
      float4 p0 = *(const float4*)(cb + (size_t)s0 * 16);
      float4 q0 = *(const float4*)(cb + (size_t)s1 * 16);
      float4 p1 = *(const float4*)(cb + (size_t)s2 * 16);
      float4 q1 = *(const float4*)(cb + (size_t)s3 * 16);
      BV bh[4], bl[4];
#pragma unroll
      for (int cg = 0; cg < 4; cg++) {
        bh[cg].q = wp[(ks * 4 + cg) * 64];
        bl[cg].q = wp[2048 + (ks * 4 + cg) * 64];
      }
      BV ah0, al0, ah1, al1;
      ah0.q.x = hi_pair(p0.x, p0.y); ah0.q.y = hi_pair(p0.z, p0.w);
      ah0.q.z = hi_pair(q0.x, q0.y); ah0.q.w = hi_pair(q0.z, q0.w);
      al0.q.x = lo_pair(p0.x, p0.y); al0.q.y = lo_pair(p0.z, p0.w);
      al0.q.z = lo_pair(q0.x, q0.y); al0.q.w = lo_pair(q0.z, q0.w);
      ah1.q.x = hi_pair(p1.x, p1.y); ah1.q.y = hi_pair(p1.z, p1.w);
      ah1.q.z = hi_pair(q1.x, q1.y); ah1.q.w = hi_pair(q1.z, q1.w);
      al1.q.x = lo_pair(p1.x, p1.y); al1.q.y = lo_pair(p1.z, p1.w);
      al1.q.z = lo_pair(q1.x, q1.y); al1.q.w = lo_pair(q1.z, q1.w);
#pragma unroll
      for (int cg = 0; cg < 4; cg++) {
        acc[0][cg] = __builtin_amdgcn_mfma_f32_16x16x32_bf16(ah0.v, bh[cg].v, acc[0][cg], 0, 0, 0);
        acc[0][cg] = __builtin_amdgcn_mfma_f32_16x16x32_bf16(al0.v, bh[cg].v, acc[0][cg], 0, 0, 0);
        acc[0][cg] = __builtin_amdgcn_mfma_f32_16x16x32_bf16(ah0.v, bl[cg].v, acc[0][cg], 0, 0, 0);
        acc[1][cg] = __builtin_amdgcn_mfma_f32_16x16x32_bf16(ah1.v, bh[cg].v, acc[1][cg], 0, 0, 0);
        acc[1][cg] = __builtin_amdgcn_mfma_f32_16x16x32_bf16(al1.v, bh[cg].v, acc[1][cg], 0, 0, 0);
        acc[1][cg] = __builtin_amdgcn_mfma_f32_16x16x32_bf16(ah1.v, bl[cg].v, acc[1][cg], 0, 0, 0);
      }
      __syncthreads();   // prefetch landed for all waves + WAR protection
    }
#undef STAGE

    // epilogue. C/D layout: col = cg*16 + lr, row(node) = rg*16 + 4*lg + tt.
    int r0 = r0blk + wv * 32;
#pragma unroll
    for (int rg = 0; rg < 2; rg++) {
#pragma unroll
      for (int tt = 0; tt < 4; tt++) {
        int node = r0 + rg * 16 + 4 * lg + tt;
        bool ok = node < N;
        float v0 = acc[rg][0][tt], v1 = acc[rg][1][tt], v2 = acc[rg][2][tt], v3 = acc[rg][3][tt];
        float o0 = __shfl_xor(v0, 1), o1 = __shfl_xor(v1, 1);
        float o2 = __shfl_xor(v2, 1), o3 = __shfl_xor(v3, 1);
        if (ok && !(l & 1)) {
          size_t hb = (size_t)node * 32 + (lr >> 1);
          h2[hb]      = __halves2half2(__float2half_rn(v0), __float2half_rn(o0));
          h2[hb + 8]  = __halves2half2(__float2half_rn(v1), __float2half_rn(o1));
          h2[hb + 16] = __halves2half2(__float2half_rn(v2), __float2half_rn(o2));
          h2[hb + 24] = __halves2half2(__float2half_rn(v3), __float2half_rn(o3));
        }
#pragma unroll
        for (int cg = 0; cg < 4; cg++) {
          float v = (cg == 0) ? v0 : (cg == 1) ? v1 : (cg == 2) ? v2 : v3;
          float s = v * as4[cg];
          float d = v * ad4[cg];
          s += __shfl_xor(s, 1); d += __shfl_xor(d, 1);
          s += __shfl_xor(s, 2); d += __shfl_xor(d, 2);
          s += __shfl_xor(s, 4); d += __shfl_xor(d, 4);
          if (ok && !(l & 7)) {
            int hd = 2 * cg + (lr >> 3);
            asrc[node * NHEAD + hd] = s;
            adst[node * NHEAD + hd] = d;
          }
        }
      }
    }
    return;
  }

  // ================= partition half (R2 version verbatim) =================
  int base = idx * 8192;
  int cblk = min(8192, E - base);
  for (int i = t; i < 1024; i += 512) hist[i] = 0;
  __syncthreads();
#pragma unroll
  for (int j = 0; j < 16; j++) {
    int e = base + j * 512 + t;
    if (e < E) atomicAdd(&hist[edge[E + e] >> BSH], 1);
  }
  __syncthreads();
  int a = hist[2 * t], bb = hist[2 * t + 1];
  pr[t] = a + bb;
  __syncthreads();
  for (int off = 1; off < 512; off <<= 1) {
    int add = (t >= off) ? pr[t - off] : 0;
    __syncthreads();
    pr[t] += add;
    __syncthreads();
  }
  int excl = pr[t] - (a + bb);
  loff[2 * t] = excl;
  loff[2 * t + 1] = excl + a;
  if (a > 0 && 2 * t < NB) basearr[2 * t] = atomicAdd(&bcursor[2 * t], a);
  if (bb > 0 && 2 * t + 1 < NB) basearr[2 * t + 1] = atomicAdd(&bcursor[2 * t + 1], bb);
  hist[2 * t] = excl;           // reuse hist as LDS scatter cursor
  hist[2 * t + 1] = excl + a;
  __syncthreads();
#pragma unroll
  for (int j = 0; j < 16; j++) {
    int e = base + j * 512 + t;
    if (e < E) {
      int s = edge[e], d = edge[E + e];
      int p = atomicAdd(&hist[d >> BSH], 1);
      srt8[p] = ((unsigned long long)(unsigned int)d << 32) | (unsigned int)s;
    }
  }
  __syncthreads();
  for (int i = t; i < cblk; i += 512) {
    unsigned long long v = srt8[i];
    int d = (int)(v >> 32), s = (int)(v & 0xFFFFFFFFu);
    int bk = d >> BSH;
    int local = basearr[bk] + (i - loff[bk]);
    if (local < CAP)
      entries[(size_t)bk * CAP + local] = ((unsigned int)(d & (BSZ - 1)) << 17) | (unsigned int)s;
  }
}

// TWO blocks per bucket, split by DST-HALF. R14 edits (vs R12):
// (1) REGISTER-CACHED bucket scan: each thread loads its <=11 entries ONCE
//     (unrolled, compile-time indexed), histograms from regs, scatters from
//     regs -- eliminates the second full-bucket global pass (~25MB L2-side).
//     Sentinel 0xFFFFFFFF yields d=32767 -> fails (d>>6)==hf, auto-skipped.
// (2) shfl-based 64-bin prefix scan inside wave 0 (t<64 <=> wave 0): 12
//     barriers -> 2.
// Agg unchanged: lane l = (edge-slot l>>3, head l&7), ONE uint4 h2 load +
// ONE asrc load + ONE exp per edge-lane.
__global__ __launch_bounds__(512, 6) void k_bagg(
    const unsigned int* __restrict__ entries, const int* __restrict__ bcursor,
    const __half2* __restrict__ h2, const float* __restrict__ asrc,
    const float* __restrict__ adst, const float* __restrict__ bias,
    float* __restrict__ out, int N) {
  __shared__ int srt[HCAP];
  __shared__ int hist[64];
  __shared__ int cur[64];
  __shared__ int off[65];
  int t = threadIdx.x;
  int bkt = blockIdx.x >> 1;
  int hf = blockIdx.x & 1;
  int n0 = (bkt << BSH) + (hf << 6);
  int ncnt = min(64, N - n0);
  if (ncnt <= 0) return;  // uniform across block: safe before barriers
  int cnt = bcursor[bkt];
  if (cnt > CAP) cnt = CAP;
  const unsigned int* ebase = entries + (size_t)bkt * CAP;
  if (t < 64) hist[t] = 0;
  __syncthreads();
  // single global pass: load this thread's entries into registers
  unsigned int ev[11];  // ceil(CAP/512) = 11
#pragma unroll
  for (int j = 0; j < 11; j++) {
    int i = t + j * 512;
    ev[j] = (i < cnt) ? ebase[i] : 0xFFFFFFFFu;
  }
  // histogram from registers
#pragma unroll
  for (int j = 0; j < 11; j++) {
    int d = (int)(ev[j] >> 17);
    if ((d >> 6) == hf) atomicAdd(&hist[d & 63], 1);
  }
  __syncthreads();
  // prefix scan of 64 bins entirely within wave 0 (t<64 <=> wave 0)
  if (t < 64) {
    int orig = hist[t];
    int v = orig;
#pragma unroll
    for (int o = 1; o < 64; o <<= 1) {
      int u = __shfl_up(v, o);
      if (t >= o) v += u;
    }
    off[t] = v - orig;
    cur[t] = v - orig;
    if (t == 63) off[64] = v;
  }
  __syncthreads();
  // scatter from registers
#pragma unroll
  for (int j = 0; j < 11; j++) {
    unsigned int v = ev[j];
    int d = (int)(v >> 17);
    if ((d >> 6) == hf) {
      int p = atomicAdd(&cur[d & 63], 1);
      if (p < HCAP) srt[p] = (int)(v & 0x1FFFF);
    }
  }
  __syncthreads();
  int wv = t >> 6, l = t & 63;
  int eslot = l >> 3, cg = l & 7;
  for (int nd = wv; nd < ncnt; nd += 8) {
    int node = n0 + nd;
    int sbeg = min(off[nd], HCAP), send = min(off[nd + 1], HCAP);
    float ad = adst[node * NHEAD + cg];
    float a0 = 0.f, a1 = 0.f, a2 = 0.f, a3 = 0.f;
    float a4 = 0.f, a5 = 0.f, a6 = 0.f, a7 = 0.f;
    float wsum = 0.f;
    for (int k = sbeg; k < send; k += 8) {
      int idx = k + eslot;
      bool val = idx < send;
      int s = srt[val ? idx : send - 1];
      float lg = asrc[s * NHEAD + cg] + ad;
      float w = __expf(fmaxf(lg, NEG * lg));
      w = val ? w : 0.f;
      union { uint4 q; __half2 h[4]; } u;
      u.q = *((const uint4*)(h2 + (size_t)s * 32) + cg);
      float2 f0 = __half22float2(u.h[0]);
      float2 f1 = __half22float2(u.h[1]);
      float2 f2 = __half22float2(u.h[2]);
      float2 f3 = __half22float2(u.h[3]);
      a0 = fmaf(w, f0.x, a0); a1 = fmaf(w, f0.y, a1);
      a2 = fmaf(w, f1.x, a2); a3 = fmaf(w, f1.y, a3);
      a4 = fmaf(w, f2.x, a4); a5 = fmaf(w, f2.y, a5);
      a6 = fmaf(w, f3.x, a6); a7 = fmaf(w, f3.y, a7);
      wsum += w;
    }
#pragma unroll
    for (int m = 8; m < 64; m <<= 1) {
      a0 += __shfl_xor(a0, m); a1 += __shfl_xor(a1, m);
      a2 += __shfl_xor(a2, m); a3 += __shfl_xor(a3, m);
      a4 += __shfl_xor(a4, m); a5 += __shfl_xor(a5, m);
      a6 += __shfl_xor(a6, m); a7 += __shfl_xor(a7, m);
      wsum += __shfl_xor(wsum, m);
    }
    if (l < 8) {
      float inv = wsum > 0.f ? 1.0f / wsum : 0.f;
      float4 b0 = *(const float4*)&bias[cg * 8];
      float4 b1 = *(const float4*)&bias[cg * 8 + 4];
      float4 r0, r1;
      r0.x = fmaf(a0, inv, b0.x); r0.y = fmaf(a1, inv, b0.y);
      r0.z = fmaf(a2, inv, b0.z); r0.w = fmaf(a3, inv, b0.w);
      r1.x = fmaf(a4, inv, b1.x); r1.y = fmaf(a5, inv, b1.y);
      r1.z = fmaf(a6, inv, b1.z); r1.w = fmaf(a7, inv, b1.w);
      *(float4*)&out[(size_t)node * HC + cg * 8] = r0;
      *(float4*)&out[(size_t)node * HC + cg * 8 + 4] = r1;
    }
  }
}

extern "C" void kernel_launch(void* const* d_in, const int* in_sizes, int n_in,
                              void* d_out, int out_size, void* d_ws, size_t ws_size,
                              hipStream_t stream) {
  const float* x = (const float*)d_in[0];
  const int* edge = (const int*)d_in[1];
  const float* W = (const float*)d_in[2];
  const float* att_src = (const float*)d_in[3];
  const float* att_dst = (const float*)d_in[4];
  const float* bias = (const float*)d_in[5];
  int N = in_sizes[0] / F_IN;
  int E = in_sizes[1] / 2;
  float* out = (float*)d_out;
  int NB = (N + BSZ - 1) >> BSH;

  // workspace layout (Wp first: keeps 16B alignment for uint4 fragment loads)
  unsigned short* Wp = (unsigned short*)d_ws;             // 32768 bf16 = 64 KB
  __half2* h2 = (__half2*)((char*)d_ws + 65536);          // N*32 half2 (= N*64 fp16)
  float* asrc = (float*)(h2 + (size_t)N * 32);            // N*8
  float* adst = asrc + (size_t)N * NHEAD;                 // N*8
  int* bcursor = (int*)(adst + (size_t)N * NHEAD);        // NB (padded to 16B)
  unsigned int* entries = (unsigned int*)(bcursor + ((NB + 3) & ~3));  // NB*CAP

  int NG = (N + 255) / 256;       // gemm blocks (256 rows each)
  int NP = (E + 8191) / 8192;     // partition chunks
  int nzb = (NB + 255) / 256;

  k_prep<<<64 + nzb, 256, 0, stream>>>(W, Wp, bcursor, NB);
  k_fused<<<NG + NP, 512, 0, stream>>>(x, (const uint4*)Wp, att_src, att_dst,
                                       h2, asrc, adst, edge, bcursor, entries,
                                       N, E, NB, NG, NP);
  k_bagg<<<2 * NB, 512, 0, stream>>>(entries, bcursor, h2, asrc, adst, bias, out, N);
}